// Round 1
// baseline (312.628 us; speedup 1.0000x reference)
//
#include <hip/hip_runtime.h>
#include <hip/hip_bf16.h>
#include <stdint.h>

typedef unsigned short u16;
typedef __attribute__((ext_vector_type(8))) short short8;   // 8 x bf16 (4 VGPRs) MFMA A/B frag
typedef __attribute__((ext_vector_type(4))) float floatx4;  // MFMA C/D frag

#define BATCH 4
#define SEQ   2048
#define DIM   1024

__device__ inline u16 f2bf(float f) {
  union { float f; uint32_t u; } v; v.f = f;
  uint32_t r = v.u + 0x7fffu + ((v.u >> 16) & 1u);  // RNE
  return (u16)(r >> 16);
}
__device__ inline float bf2f(u16 h) {
  union { uint32_t u; float f; } v; v.u = ((uint32_t)h) << 16;
  return v.f;
}

// async global->LDS, 16B per lane; LDS dest must be wave-uniform base (+lane*16 by HW)
__device__ inline void gload_lds16(const u16* g, u16* l) {
  __builtin_amdgcn_global_load_lds((const __attribute__((address_space(1))) uint32_t*)g,
                                   (__attribute__((address_space(3))) uint32_t*)l,
                                   16, 0, 0);
}

// ---------------- elementwise fp32 -> bf16 ----------------
__global__ __launch_bounds__(256) void cvt_x(const float* __restrict__ in,
                                             u16* __restrict__ out) {
  size_t i = ((size_t)blockIdx.x * 256 + threadIdx.x) * 4;
  float4 v = *(const float4*)(in + i);
  ushort4 o;
  o.x = f2bf(v.x); o.y = f2bf(v.y); o.z = f2bf(v.z); o.w = f2bf(v.w);
  *(ushort4*)(out + i) = o;
}

// ---------------- W[d][h] fp32 -> Wt[h][d] bf16 (3 weights via z) ----------------
__global__ __launch_bounds__(256) void transpose_w(const float* __restrict__ Wq,
                                                   const float* __restrict__ Wk,
                                                   const float* __restrict__ Wv,
                                                   u16* __restrict__ out) {
  const float* W = (blockIdx.z == 0) ? Wq : (blockIdx.z == 1) ? Wk : Wv;
  u16* o = out + (size_t)blockIdx.z * (1u << 20);
  __shared__ u16 tile[32][33];
  int c0 = blockIdx.x * 32, r0 = blockIdx.y * 32;
  int tx = threadIdx.x & 31, ty = threadIdx.x >> 5;  // ty 0..7
#pragma unroll
  for (int p = 0; p < 4; ++p)
    tile[p * 8 + ty][tx] = f2bf(W[(size_t)(r0 + p * 8 + ty) * DIM + c0 + tx]);
  __syncthreads();
#pragma unroll
  for (int p = 0; p < 4; ++p)
    o[(size_t)(c0 + p * 8 + ty) * DIM + r0 + tx] = tile[tx][p * 8 + ty];
}

// ---------------- V[b][s][h] -> Vt[b][h][s] (bf16) ----------------
__global__ __launch_bounds__(256) void transpose_v(const u16* __restrict__ V,
                                                   u16* __restrict__ Vt) {
  const u16* in = V + (size_t)blockIdx.z * SEQ * DIM;
  u16* out = Vt + (size_t)blockIdx.z * SEQ * DIM;
  __shared__ u16 tile[32][33];
  int c0 = blockIdx.x * 32, r0 = blockIdx.y * 32;  // c over DIM, r over SEQ
  int tx = threadIdx.x & 31, ty = threadIdx.x >> 5;
#pragma unroll
  for (int p = 0; p < 4; ++p)
    tile[p * 8 + ty][tx] = in[(size_t)(r0 + p * 8 + ty) * DIM + c0 + tx];
  __syncthreads();
#pragma unroll
  for (int p = 0; p < 4; ++p)
    out[(size_t)(c0 + p * 8 + ty) * SEQ + r0 + tx] = tile[tx][p * 8 + ty];
}

// ---------------- pack bq,bk,bv contiguously ----------------
__global__ void gather_bias(const float* __restrict__ bq, const float* __restrict__ bk,
                            const float* __restrict__ bv, float* __restrict__ out) {
  int i = blockIdx.x * 256 + threadIdx.x;  // 0..1023
  const float* s = (blockIdx.y == 0) ? bq : (blockIdx.y == 1) ? bk : bv;
  out[blockIdx.y * 1024 + i] = s[i];
}

// ---------------- m97-style bf16 GEMM: C[m][n] = sum_k A[m][k]*Bt[n][k] ----------------
// EPI 0: +bias[col], bf16 out.  EPI 1: *scale, bf16 out.  EPI 2: fp32 out.
template <int EPI>
__global__ __launch_bounds__(256)
void gemm_bt(const u16* __restrict__ A, const u16* __restrict__ Bt,
             void* __restrict__ Cv, const float* __restrict__ bias,
             float scale, int M, int N, int K,
             size_t sA, size_t sB, size_t sC) {
  __shared__ u16 ldsA[128 * 32];
  __shared__ u16 ldsB[128 * 32];
  const int lane = threadIdx.x & 63;
  const int wave = threadIdx.x >> 6;

  const u16* Ab = A + sA * blockIdx.z + (size_t)blockIdx.y * 128 * K;
  const u16* Bb = Bt + sB * blockIdx.z + (size_t)blockIdx.x * 128 * K;

  // staging: wave w covers tile rows [w*32, w*32+32); 2 insts of 16 rows each
  const int sr = lane >> 2;          // row within 16-row group
  const int sc = (lane & 3) * 8;     // k-offset (elements), 16B chunks
  const u16* gA0 = Ab + (size_t)(wave * 32 + sr) * K + sc;
  const u16* gA1 = gA0 + (size_t)16 * K;
  const u16* gB0 = Bb + (size_t)(wave * 32 + sr) * K + sc;
  const u16* gB1 = gB0 + (size_t)16 * K;
  u16* lA0 = ldsA + wave * 1024;  // 16 rows * 32 elems = 512 elems per inst
  u16* lA1 = lA0 + 512;
  u16* lB0 = ldsB + wave * 1024;
  u16* lB1 = lB0 + 512;

  // compute: 2x2 waves, each 64x64 = 4x4 subtiles of 16x16
  const int wm = (wave >> 1) * 64;
  const int wn = (wave & 1) * 64;
  const int fr = lane & 15;
  const int fk = (lane >> 4) * 8;
  const u16* la = ldsA + (wm + fr) * 32 + fk;
  const u16* lb = ldsB + (wn + fr) * 32 + fk;

  floatx4 acc[4][4] = {};

  for (int kt = 0; kt < K; kt += 32) {
    __syncthreads();
    gload_lds16(gA0 + kt, lA0);
    gload_lds16(gA1 + kt, lA1);
    gload_lds16(gB0 + kt, lB0);
    gload_lds16(gB1 + kt, lB1);
    __syncthreads();
    short8 a[4], b[4];
#pragma unroll
    for (int i = 0; i < 4; ++i) a[i] = *(const short8*)(la + i * 512);
#pragma unroll
    for (int i = 0; i < 4; ++i) b[i] = *(const short8*)(lb + i * 512);
#pragma unroll
    for (int mi = 0; mi < 4; ++mi)
#pragma unroll
      for (int ni = 0; ni < 4; ++ni)
        acc[mi][ni] = __builtin_amdgcn_mfma_f32_16x16x32_bf16(a[mi], b[ni], acc[mi][ni], 0, 0, 0);
  }

  // epilogue: C/D layout col=lane&15, row=(lane>>4)*4+r
  const int er = (lane >> 4) * 4;
  const int ec = lane & 15;
  const int r0 = blockIdx.y * 128 + wm;
  const int c0 = blockIdx.x * 128 + wn;

  if (EPI == 0) {
    u16* C = (u16*)Cv + sC * blockIdx.z;
    const float* bz = bias + blockIdx.z * 1024;
#pragma unroll
    for (int mi = 0; mi < 4; ++mi)
#pragma unroll
      for (int ni = 0; ni < 4; ++ni) {
        const int col = c0 + ni * 16 + ec;
        const float bb = bz[col];
#pragma unroll
        for (int r = 0; r < 4; ++r) {
          const int row = r0 + mi * 16 + er + r;
          C[(size_t)row * N + col] = f2bf(acc[mi][ni][r] + bb);
        }
      }
  } else if (EPI == 1) {
    u16* C = (u16*)Cv + sC * blockIdx.z;
#pragma unroll
    for (int mi = 0; mi < 4; ++mi)
#pragma unroll
      for (int ni = 0; ni < 4; ++ni) {
        const int col = c0 + ni * 16 + ec;
#pragma unroll
        for (int r = 0; r < 4; ++r) {
          const int row = r0 + mi * 16 + er + r;
          C[(size_t)row * N + col] = f2bf(acc[mi][ni][r] * scale);
        }
      }
  } else {
    float* C = (float*)Cv + sC * blockIdx.z;
#pragma unroll
    for (int mi = 0; mi < 4; ++mi)
#pragma unroll
      for (int ni = 0; ni < 4; ++ni) {
        const int col = c0 + ni * 16 + ec;
#pragma unroll
        for (int r = 0; r < 4; ++r) {
          const int row = r0 + mi * 16 + er + r;
          C[(size_t)row * N + col] = acc[mi][ni][r];
        }
      }
  }
}

// ---------------- row softmax over 2048 bf16, in place ----------------
__global__ __launch_bounds__(256) void softmax_rows(u16* __restrict__ P) {
  const size_t row = blockIdx.x;
  u16* p = P + row * 2048 + threadIdx.x * 8;
  const int lane = threadIdx.x & 63;
  const int wave = threadIdx.x >> 6;
  __shared__ float red[8];

  u16 v[8];
  *(uint4*)v = *(const uint4*)p;
  float x[8];
#pragma unroll
  for (int i = 0; i < 8; ++i) x[i] = bf2f(v[i]);

  float m = x[0];
#pragma unroll
  for (int i = 1; i < 8; ++i) m = fmaxf(m, x[i]);
#pragma unroll
  for (int o = 32; o; o >>= 1) m = fmaxf(m, __shfl_xor(m, o));
  if (lane == 0) red[wave] = m;
  __syncthreads();
  m = fmaxf(fmaxf(red[0], red[1]), fmaxf(red[2], red[3]));

  float e[8], s = 0.f;
#pragma unroll
  for (int i = 0; i < 8; ++i) { e[i] = exp2f((x[i] - m) * 1.44269504f); s += e[i]; }
#pragma unroll
  for (int o = 32; o; o >>= 1) s += __shfl_xor(s, o);
  if (lane == 0) red[4 + wave] = s;
  __syncthreads();
  s = red[4] + red[5] + red[6] + red[7];
  const float inv = 1.0f / s;
#pragma unroll
  for (int i = 0; i < 8; ++i) v[i] = f2bf(e[i] * inv);
  *(uint4*)p = *(uint4*)v;
}

extern "C" void kernel_launch(void* const* d_in, const int* in_sizes, int n_in,
                              void* d_out, int out_size, void* d_ws, size_t ws_size,
                              hipStream_t stream) {
  const float* x  = (const float*)d_in[0];
  const float* Wq = (const float*)d_in[1];
  const float* bq = (const float*)d_in[2];
  const float* Wk = (const float*)d_in[3];
  const float* bk = (const float*)d_in[4];
  const float* Wv = (const float*)d_in[5];
  const float* bv = (const float*)d_in[6];
  float* out = (float*)d_out;

  char* ws = (char*)d_ws;
  const size_t MB = 1ull << 20;
  u16* Q    = (u16*)(ws + 0 * MB);    // [3][8192][1024] bf16: Q,K,V contiguous
  u16* Kb   = (u16*)(ws + 16 * MB);
  u16* V    = (u16*)(ws + 32 * MB);
  u16* Vt   = (u16*)(ws + 48 * MB);   // [4][1024][2048]
  u16* Xb   = (u16*)(ws + 64 * MB);   // [8192][1024]
  u16* Wt   = (u16*)(ws + 80 * MB);   // [3][1024][1024]
  float* bias = (float*)(ws + 86 * MB);  // [3][1024]
  u16* P    = (u16*)(ws + 88 * MB);   // [4][2048][2048] logits->attn, ends 120MB
  (void)Kb; (void)ws_size; (void)in_sizes; (void)n_in; (void)out_size;

  // 1) x -> bf16
  cvt_x<<<8192, 256, 0, stream>>>(x, Xb);
  // 2) W -> Wt bf16
  transpose_w<<<dim3(32, 32, 3), 256, 0, stream>>>(Wq, Wk, Wv, Wt);
  // 3) biases contiguous
  gather_bias<<<dim3(4, 3, 1), 256, 0, stream>>>(bq, bk, bv, bias);
  // 4) QKV projection: [8192,1024] x [1024,1024]^T(stored T) + bias, z = q/k/v
  gemm_bt<0><<<dim3(8, 64, 3), 256, 0, stream>>>(
      Xb, Wt, Q, bias, 1.0f, 8192, 1024, 1024,
      (size_t)0, (size_t)(1u << 20), (size_t)(8u << 20));
  // 5) V -> Vt
  transpose_v<<<dim3(32, 64, 4), 256, 0, stream>>>(V, Vt);
  // 6) scores = Q K^T / 32, bf16, z = batch
  gemm_bt<1><<<dim3(16, 16, 4), 256, 0, stream>>>(
      Q, Kb, P, nullptr, 0.03125f, 2048, 2048, 1024,
      (size_t)2097152, (size_t)2097152, (size_t)4194304);
  // 7) softmax rows
  softmax_rows<<<8192, 256, 0, stream>>>(P);
  // 8) out = P V  (A=P, Bt=Vt), fp32 out
  gemm_bt<2><<<dim3(8, 16, 4), 256, 0, stream>>>(
      P, Vt, out, nullptr, 1.0f, 2048, 1024, 2048,
      (size_t)4194304, (size_t)2097152, (size_t)2097152);
}

// Round 2
// 304.181 us; speedup vs baseline: 1.0278x; 1.0278x over previous
//
#include <hip/hip_runtime.h>
#include <hip/hip_bf16.h>
#include <stdint.h>

typedef unsigned short u16;
typedef __attribute__((ext_vector_type(8))) short short8;   // 8 x bf16 (4 VGPRs) MFMA A/B frag
typedef __attribute__((ext_vector_type(4))) float floatx4;  // MFMA C/D frag

#define BATCH 4
#define SEQ   2048
#define DIM   1024

__device__ inline u16 f2bf(float f) {
  union { float f; uint32_t u; } v; v.f = f;
  uint32_t r = v.u + 0x7fffu + ((v.u >> 16) & 1u);  // RNE
  return (u16)(r >> 16);
}
__device__ inline float bf2f(u16 h) {
  union { uint32_t u; float f; } v; v.u = ((uint32_t)h) << 16;
  return v.f;
}

// async global->LDS, 16B per lane; LDS dest must be wave-uniform base (+lane*16 by HW)
__device__ inline void gload_lds16(const u16* g, u16* l) {
  __builtin_amdgcn_global_load_lds((const __attribute__((address_space(1))) uint32_t*)g,
                                   (__attribute__((address_space(3))) uint32_t*)l,
                                   16, 0, 0);
}

// ---------------- elementwise fp32 -> bf16 ----------------
__global__ __launch_bounds__(256) void cvt_x(const float* __restrict__ in,
                                             u16* __restrict__ out) {
  size_t i = ((size_t)blockIdx.x * 256 + threadIdx.x) * 4;
  float4 v = *(const float4*)(in + i);
  ushort4 o;
  o.x = f2bf(v.x); o.y = f2bf(v.y); o.z = f2bf(v.z); o.w = f2bf(v.w);
  *(ushort4*)(out + i) = o;
}

// ---------------- W[d][h] fp32 -> Wt[h][d] bf16 (3 weights via z) ----------------
__global__ __launch_bounds__(256) void transpose_w(const float* __restrict__ Wq,
                                                   const float* __restrict__ Wk,
                                                   const float* __restrict__ Wv,
                                                   u16* __restrict__ out) {
  const float* W = (blockIdx.z == 0) ? Wq : (blockIdx.z == 1) ? Wk : Wv;
  u16* o = out + (size_t)blockIdx.z * (1u << 20);
  __shared__ u16 tile[32][33];
  int c0 = blockIdx.x * 32, r0 = blockIdx.y * 32;
  int tx = threadIdx.x & 31, ty = threadIdx.x >> 5;  // ty 0..7
#pragma unroll
  for (int p = 0; p < 4; ++p)
    tile[p * 8 + ty][tx] = f2bf(W[(size_t)(r0 + p * 8 + ty) * DIM + c0 + tx]);
  __syncthreads();
#pragma unroll
  for (int p = 0; p < 4; ++p)
    o[(size_t)(c0 + p * 8 + ty) * DIM + r0 + tx] = tile[tx][p * 8 + ty];
}

// ---------------- V[b][s][h] -> Vt[b][h][s] (bf16) ----------------
__global__ __launch_bounds__(256) void transpose_v(const u16* __restrict__ V,
                                                   u16* __restrict__ Vt) {
  const u16* in = V + (size_t)blockIdx.z * SEQ * DIM;
  u16* out = Vt + (size_t)blockIdx.z * SEQ * DIM;
  __shared__ u16 tile[32][33];
  int c0 = blockIdx.x * 32, r0 = blockIdx.y * 32;  // c over DIM, r over SEQ
  int tx = threadIdx.x & 31, ty = threadIdx.x >> 5;
#pragma unroll
  for (int p = 0; p < 4; ++p)
    tile[p * 8 + ty][tx] = in[(size_t)(r0 + p * 8 + ty) * DIM + c0 + tx];
  __syncthreads();
#pragma unroll
  for (int p = 0; p < 4; ++p)
    out[(size_t)(c0 + p * 8 + ty) * SEQ + r0 + tx] = tile[tx][p * 8 + ty];
}

// ---------------- pack bq,bk,bv contiguously ----------------
__global__ void gather_bias(const float* __restrict__ bq, const float* __restrict__ bk,
                            const float* __restrict__ bv, float* __restrict__ out) {
  int i = blockIdx.x * 256 + threadIdx.x;  // 0..1023
  const float* s = (blockIdx.y == 0) ? bq : (blockIdx.y == 1) ? bk : bv;
  out[blockIdx.y * 1024 + i] = s[i];
}

// ---------------- m97-style bf16 GEMM: C[m][n] = sum_k A[m][k]*Bt[n][k] ----------------
// EPI 0: +bias[col], bf16 out.  EPI 1: *scale, bf16 out.  EPI 2: fp32 out.
// SWIZ 0: grid(64,8,z): mt=x, nt=y            (xcd = mt%8 -> A-stripe resident per XCD)
// SWIZ 1: grid(256,1,z): 4m x 8n super-tile per XCD
// SWIZ 2: grid(128,1,z): 4m x 4n super-tile per XCD
template <int EPI, int SWIZ>
__global__ __launch_bounds__(256)
void gemm_bt(const u16* __restrict__ A, const u16* __restrict__ Bt,
             void* __restrict__ Cv, const float* __restrict__ bias,
             float scale, int M, int N, int K,
             size_t sA, size_t sB, size_t sC) {
  __shared__ u16 ldsA[128 * 32];
  __shared__ u16 ldsB[128 * 32];
  const int lane = threadIdx.x & 63;
  const int wave = threadIdx.x >> 6;

  int mt, nt;
  if (SWIZ == 0) {
    mt = blockIdx.x; nt = blockIdx.y;
  } else if (SWIZ == 1) {
    const int lin = blockIdx.x;            // 0..255
    const int c = lin & 7, j = lin >> 3;   // xcd-slot, index within slot
    mt = 4 * (c & 3) + (j & 3);            // 16 m-tiles
    nt = 8 * (c >> 2) + (j >> 2);          // 16 n-tiles
  } else {
    const int lin = blockIdx.x;            // 0..127
    const int c = lin & 7, j = lin >> 3;
    mt = 4 * (c >> 1) + (j & 3);           // 16 m-tiles
    nt = 4 * (c & 1) + (j >> 2);           // 8 n-tiles
  }

  const u16* Ab = A + sA * blockIdx.z + (size_t)mt * 128 * K;
  const u16* Bb = Bt + sB * blockIdx.z + (size_t)nt * 128 * K;

  // staging: wave w covers tile rows [w*32, w*32+32); 2 insts of 16 rows each
  const int sr = lane >> 2;          // row within 16-row group
  const int sc = (lane & 3) * 8;     // k-offset (elements), 16B chunks
  const u16* gA0 = Ab + (size_t)(wave * 32 + sr) * K + sc;
  const u16* gA1 = gA0 + (size_t)16 * K;
  const u16* gB0 = Bb + (size_t)(wave * 32 + sr) * K + sc;
  const u16* gB1 = gB0 + (size_t)16 * K;
  u16* lA0 = ldsA + wave * 1024;  // 16 rows * 32 elems = 512 elems per inst
  u16* lA1 = lA0 + 512;
  u16* lB0 = ldsB + wave * 1024;
  u16* lB1 = lB0 + 512;

  // compute: 2x2 waves, each 64x64 = 4x4 subtiles of 16x16
  const int wm = (wave >> 1) * 64;
  const int wn = (wave & 1) * 64;
  const int fr = lane & 15;
  const int fk = (lane >> 4) * 8;
  const u16* la = ldsA + (wm + fr) * 32 + fk;
  const u16* lb = ldsB + (wn + fr) * 32 + fk;

  floatx4 acc[4][4] = {};

  for (int kt = 0; kt < K; kt += 32) {
    __syncthreads();
    gload_lds16(gA0 + kt, lA0);
    gload_lds16(gA1 + kt, lA1);
    gload_lds16(gB0 + kt, lB0);
    gload_lds16(gB1 + kt, lB1);
    __syncthreads();
    short8 a[4], b[4];
#pragma unroll
    for (int i = 0; i < 4; ++i) a[i] = *(const short8*)(la + i * 512);
#pragma unroll
    for (int i = 0; i < 4; ++i) b[i] = *(const short8*)(lb + i * 512);
#pragma unroll
    for (int mi = 0; mi < 4; ++mi)
#pragma unroll
      for (int ni = 0; ni < 4; ++ni)
        acc[mi][ni] = __builtin_amdgcn_mfma_f32_16x16x32_bf16(a[mi], b[ni], acc[mi][ni], 0, 0, 0);
  }

  // epilogue: C/D layout col=lane&15, row=(lane>>4)*4+r
  const int er = (lane >> 4) * 4;
  const int ec = lane & 15;
  const int r0 = mt * 128 + wm;
  const int c0 = nt * 128 + wn;

  if (EPI == 0) {
    u16* C = (u16*)Cv + sC * blockIdx.z;
    const float* bz = bias + blockIdx.z * 1024;
#pragma unroll
    for (int mi = 0; mi < 4; ++mi)
#pragma unroll
      for (int ni = 0; ni < 4; ++ni) {
        const int col = c0 + ni * 16 + ec;
        const float bb = bz[col];
#pragma unroll
        for (int r = 0; r < 4; ++r) {
          const int row = r0 + mi * 16 + er + r;
          C[(size_t)row * N + col] = f2bf(acc[mi][ni][r] + bb);
        }
      }
  } else if (EPI == 1) {
    u16* C = (u16*)Cv + sC * blockIdx.z;
#pragma unroll
    for (int mi = 0; mi < 4; ++mi)
#pragma unroll
      for (int ni = 0; ni < 4; ++ni) {
        const int col = c0 + ni * 16 + ec;
#pragma unroll
        for (int r = 0; r < 4; ++r) {
          const int row = r0 + mi * 16 + er + r;
          C[(size_t)row * N + col] = f2bf(acc[mi][ni][r] * scale);
        }
      }
  } else {
    float* C = (float*)Cv + sC * blockIdx.z;
#pragma unroll
    for (int mi = 0; mi < 4; ++mi)
#pragma unroll
      for (int ni = 0; ni < 4; ++ni) {
        const int col = c0 + ni * 16 + ec;
#pragma unroll
        for (int r = 0; r < 4; ++r) {
          const int row = r0 + mi * 16 + er + r;
          C[(size_t)row * N + col] = acc[mi][ni][r];
        }
      }
  }
}

// ---------------- row softmax over 2048 bf16, in place ----------------
__global__ __launch_bounds__(256) void softmax_rows(u16* __restrict__ P) {
  const size_t row = blockIdx.x;
  u16* p = P + row * 2048 + threadIdx.x * 8;
  const int lane = threadIdx.x & 63;
  const int wave = threadIdx.x >> 6;
  __shared__ float red[8];

  u16 v[8];
  *(uint4*)v = *(const uint4*)p;
  float x[8];
#pragma unroll
  for (int i = 0; i < 8; ++i) x[i] = bf2f(v[i]);

  float m = x[0];
#pragma unroll
  for (int i = 1; i < 8; ++i) m = fmaxf(m, x[i]);
#pragma unroll
  for (int o = 32; o; o >>= 1) m = fmaxf(m, __shfl_xor(m, o));
  if (lane == 0) red[wave] = m;
  __syncthreads();
  m = fmaxf(fmaxf(red[0], red[1]), fmaxf(red[2], red[3]));

  float e[8], s = 0.f;
#pragma unroll
  for (int i = 0; i < 8; ++i) { e[i] = exp2f((x[i] - m) * 1.44269504f); s += e[i]; }
#pragma unroll
  for (int o = 32; o; o >>= 1) s += __shfl_xor(s, o);
  if (lane == 0) red[4 + wave] = s;
  __syncthreads();
  s = red[4] + red[5] + red[6] + red[7];
  const float inv = 1.0f / s;
#pragma unroll
  for (int i = 0; i < 8; ++i) v[i] = f2bf(e[i] * inv);
  *(uint4*)p = *(uint4*)v;
}

extern "C" void kernel_launch(void* const* d_in, const int* in_sizes, int n_in,
                              void* d_out, int out_size, void* d_ws, size_t ws_size,
                              hipStream_t stream) {
  const float* x  = (const float*)d_in[0];
  const float* Wq = (const float*)d_in[1];
  const float* bq = (const float*)d_in[2];
  const float* Wk = (const float*)d_in[3];
  const float* bk = (const float*)d_in[4];
  const float* Wv = (const float*)d_in[5];
  const float* bv = (const float*)d_in[6];
  float* out = (float*)d_out;

  char* ws = (char*)d_ws;
  const size_t MB = 1ull << 20;
  u16* Q    = (u16*)(ws + 0 * MB);    // [3][8192][1024] bf16: Q,K,V contiguous
  u16* Kb   = (u16*)(ws + 16 * MB);
  u16* V    = (u16*)(ws + 32 * MB);
  u16* Vt   = (u16*)(ws + 48 * MB);   // [4][1024][2048]
  u16* Xb   = (u16*)(ws + 64 * MB);   // [8192][1024]
  u16* Wt   = (u16*)(ws + 80 * MB);   // [3][1024][1024]
  float* bias = (float*)(ws + 86 * MB);  // [3][1024]
  u16* P    = (u16*)(ws + 88 * MB);   // [4][2048][2048] logits->attn, ends 120MB
  (void)Kb; (void)ws_size; (void)in_sizes; (void)n_in; (void)out_size;

  // 1) x -> bf16
  cvt_x<<<8192, 256, 0, stream>>>(x, Xb);
  // 2) W -> Wt bf16
  transpose_w<<<dim3(32, 32, 3), 256, 0, stream>>>(Wq, Wk, Wv, Wt);
  // 3) biases contiguous
  gather_bias<<<dim3(4, 3, 1), 256, 0, stream>>>(bq, bk, bv, bias);
  // 4) QKV projection: [8192,1024] x Wt + bias, z = q/k/v.  m-tiles fastest -> A-stripe per XCD.
  gemm_bt<0, 0><<<dim3(64, 8, 3), 256, 0, stream>>>(
      Xb, Wt, Q, bias, 1.0f, 8192, 1024, 1024,
      (size_t)0, (size_t)(1u << 20), (size_t)(8u << 20));
  // 5) V -> Vt
  transpose_v<<<dim3(32, 64, 4), 256, 0, stream>>>(V, Vt);
  // 6) scores = Q K^T / 32, bf16, z = batch.  4x8 super-tile per XCD.
  gemm_bt<1, 1><<<dim3(256, 1, 4), 256, 0, stream>>>(
      Q, Kb, P, nullptr, 0.03125f, 2048, 2048, 1024,
      (size_t)2097152, (size_t)2097152, (size_t)4194304);
  // 7) softmax rows
  softmax_rows<<<8192, 256, 0, stream>>>(P);
  // 8) out = P V  (A=P, Bt=Vt), fp32 out.  4x4 super-tile per XCD.
  gemm_bt<2, 2><<<dim3(128, 1, 4), 256, 0, stream>>>(
      P, Vt, out, nullptr, 1.0f, 2048, 1024, 2048,
      (size_t)4194304, (size_t)2097152, (size_t)2097152);
}

// Round 3
// 296.157 us; speedup vs baseline: 1.0556x; 1.0271x over previous
//
#include <hip/hip_runtime.h>
#include <hip/hip_bf16.h>
#include <stdint.h>

typedef unsigned short u16;
typedef __attribute__((ext_vector_type(8))) short short8;   // 8 x bf16 (4 VGPRs) MFMA A/B frag
typedef __attribute__((ext_vector_type(4))) float floatx4;  // MFMA C/D frag

#define BATCH 4
#define SEQ   2048
#define DIM   1024

__device__ inline u16 f2bf(float f) {
  union { float f; uint32_t u; } v; v.f = f;
  uint32_t r = v.u + 0x7fffu + ((v.u >> 16) & 1u);  // RNE
  return (u16)(r >> 16);
}
__device__ inline float bf2f(u16 h) {
  union { uint32_t u; float f; } v; v.u = ((uint32_t)h) << 16;
  return v.f;
}

// async global->LDS, 16B per lane; LDS dest must be wave-uniform base (+lane*16 by HW)
__device__ inline void gload_lds16(const u16* g, u16* l) {
  __builtin_amdgcn_global_load_lds((const __attribute__((address_space(1))) uint32_t*)g,
                                   (__attribute__((address_space(3))) uint32_t*)l,
                                   16, 0, 0);
}

// ---------------- elementwise fp32 -> bf16 (+ zero the rowsum buffer) ----------------
__global__ __launch_bounds__(256) void cvt_x(const float* __restrict__ in,
                                             u16* __restrict__ out,
                                             float* __restrict__ lsum) {
  size_t i = ((size_t)blockIdx.x * 256 + threadIdx.x) * 4;
  float4 v = *(const float4*)(in + i);
  ushort4 o;
  o.x = f2bf(v.x); o.y = f2bf(v.y); o.z = f2bf(v.z); o.w = f2bf(v.w);
  *(ushort4*)(out + i) = o;
  if (blockIdx.x < 8) {  // zero 8192 floats of lsum
    float4 z = {0.f, 0.f, 0.f, 0.f};
    *(float4*)(lsum + (size_t)blockIdx.x * 1024 + threadIdx.x * 4) = z;
  }
}

// ---------------- W[d][h] fp32 -> Wt[h][d] bf16 (3 weights via z) ----------------
__global__ __launch_bounds__(256) void transpose_w(const float* __restrict__ Wq,
                                                   const float* __restrict__ Wk,
                                                   const float* __restrict__ Wv,
                                                   u16* __restrict__ out) {
  const float* W = (blockIdx.z == 0) ? Wq : (blockIdx.z == 1) ? Wk : Wv;
  u16* o = out + (size_t)blockIdx.z * (1u << 20);
  __shared__ u16 tile[32][33];
  int c0 = blockIdx.x * 32, r0 = blockIdx.y * 32;
  int tx = threadIdx.x & 31, ty = threadIdx.x >> 5;  // ty 0..7
#pragma unroll
  for (int p = 0; p < 4; ++p)
    tile[p * 8 + ty][tx] = f2bf(W[(size_t)(r0 + p * 8 + ty) * DIM + c0 + tx]);
  __syncthreads();
#pragma unroll
  for (int p = 0; p < 4; ++p)
    o[(size_t)(c0 + p * 8 + ty) * DIM + r0 + tx] = tile[tx][p * 8 + ty];
}

// ---------------- V[b][s][h] -> Vt[b][h][s] (bf16) ----------------
__global__ __launch_bounds__(256) void transpose_v(const u16* __restrict__ V,
                                                   u16* __restrict__ Vt) {
  const u16* in = V + (size_t)blockIdx.z * SEQ * DIM;
  u16* out = Vt + (size_t)blockIdx.z * SEQ * DIM;
  __shared__ u16 tile[32][33];
  int c0 = blockIdx.x * 32, r0 = blockIdx.y * 32;  // c over DIM, r over SEQ
  int tx = threadIdx.x & 31, ty = threadIdx.x >> 5;
#pragma unroll
  for (int p = 0; p < 4; ++p)
    tile[p * 8 + ty][tx] = in[(size_t)(r0 + p * 8 + ty) * DIM + c0 + tx];
  __syncthreads();
#pragma unroll
  for (int p = 0; p < 4; ++p)
    out[(size_t)(c0 + p * 8 + ty) * SEQ + r0 + tx] = tile[tx][p * 8 + ty];
}

// ---------------- pack bq,bk,bv contiguously ----------------
__global__ void gather_bias(const float* __restrict__ bq, const float* __restrict__ bk,
                            const float* __restrict__ bv, float* __restrict__ out) {
  int i = blockIdx.x * 256 + threadIdx.x;  // 0..1023
  const float* s = (blockIdx.y == 0) ? bq : (blockIdx.y == 1) ? bk : bv;
  out[blockIdx.y * 1024 + i] = s[i];
}

// ---------------- m97-style bf16 GEMM: C[m][n] = sum_k A[m][k]*Bt[n][k] ----------------
// LDS chunk-XOR swizzle: row r's 16B k-chunk c stored at slot (c ^ (r&3)) -> breaks
// the 64B-stride 4-way bank aliasing of fragment ds_read_b128 while keeping the
// global staging 64B-coalesced (lanes of a row just load chunks in permuted order).
// EPI 0: (acc+bias[col])*zscale (zscale=1/32 for z==0: folds attention scale into Q), bf16 out.
// EPI 1: exp(acc), bf16 out, atomicAdd per-row sums into lsum (softmax denominator).
// EPI 2: acc * (1/lsum[row]), fp32 out (softmax normalization folded into PV).
// SWIZ 0: grid(64,8,z): mt=x, nt=y  (xcd = mt%8 -> A-stripe resident per XCD)
// SWIZ 1: grid(256,1,z): 4m x 8n super-tile per XCD
// SWIZ 2: grid(128,1,z): 4m x 4n super-tile per XCD
template <int EPI, int SWIZ>
__global__ __launch_bounds__(256)
void gemm_bt(const u16* __restrict__ A, const u16* __restrict__ Bt,
             void* __restrict__ Cv, const float* __restrict__ bias,
             float* __restrict__ lsum, int M, int N, int K,
             size_t sA, size_t sB, size_t sC) {
  __shared__ u16 ldsA[128 * 32];
  __shared__ u16 ldsB[128 * 32];
  const int lane = threadIdx.x & 63;
  const int wave = threadIdx.x >> 6;

  int mt, nt;
  if (SWIZ == 0) {
    mt = blockIdx.x; nt = blockIdx.y;
  } else if (SWIZ == 1) {
    const int lin = blockIdx.x;            // 0..255
    const int c = lin & 7, j = lin >> 3;   // xcd-slot, index within slot
    mt = 4 * (c & 3) + (j & 3);            // 16 m-tiles
    nt = 8 * (c >> 2) + (j >> 2);          // 16 n-tiles
  } else {
    const int lin = blockIdx.x;            // 0..127
    const int c = lin & 7, j = lin >> 3;
    mt = 4 * (c >> 1) + (j & 3);           // 16 m-tiles
    nt = 4 * (c & 1) + (j >> 2);           // 8 n-tiles
  }

  const u16* Ab = A + sA * blockIdx.z + (size_t)mt * 128 * K;
  const u16* Bb = Bt + sB * blockIdx.z + (size_t)nt * 128 * K;

  // staging: wave w covers tile rows [w*32, w*32+32); 2 insts of 16 rows each.
  // lane loads chunk ((lane&3) ^ (row&3)) so LDS slot (lane&3) holds swizzled chunk.
  const int sr = lane >> 2;                        // row within 16-row group
  const int scx = ((lane & 3) ^ (sr & 3)) * 8;     // swizzled k-offset (elements)
  const u16* gA0 = Ab + (size_t)(wave * 32 + sr) * K + scx;
  const u16* gA1 = gA0 + (size_t)16 * K;           // row+16: (row&3) unchanged
  const u16* gB0 = Bb + (size_t)(wave * 32 + sr) * K + scx;
  const u16* gB1 = gB0 + (size_t)16 * K;
  u16* lA0 = ldsA + wave * 1024;  // 16 rows * 32 elems = 512 elems per inst
  u16* lA1 = lA0 + 512;
  u16* lB0 = ldsB + wave * 1024;
  u16* lB1 = lB0 + 512;

  // compute: 2x2 waves, each 64x64 = 4x4 subtiles of 16x16
  const int wm = (wave >> 1) * 64;
  const int wn = (wave & 1) * 64;
  const int fr = lane & 15;
  const int fkx = (((lane >> 4) ^ (fr & 3))) * 8;  // swizzled fragment k-chunk
  const u16* la = ldsA + (wm + fr) * 32 + fkx;
  const u16* lb = ldsB + (wn + fr) * 32 + fkx;

  floatx4 acc[4][4] = {};

  for (int kt = 0; kt < K; kt += 32) {
    __syncthreads();
    gload_lds16(gA0 + kt, lA0);
    gload_lds16(gA1 + kt, lA1);
    gload_lds16(gB0 + kt, lB0);
    gload_lds16(gB1 + kt, lB1);
    __syncthreads();
    short8 a[4], b[4];
#pragma unroll
    for (int i = 0; i < 4; ++i) a[i] = *(const short8*)(la + i * 512);
#pragma unroll
    for (int i = 0; i < 4; ++i) b[i] = *(const short8*)(lb + i * 512);
#pragma unroll
    for (int mi = 0; mi < 4; ++mi)
#pragma unroll
      for (int ni = 0; ni < 4; ++ni)
        acc[mi][ni] = __builtin_amdgcn_mfma_f32_16x16x32_bf16(a[mi], b[ni], acc[mi][ni], 0, 0, 0);
  }

  // epilogue: C/D layout col=lane&15, row=(lane>>4)*4+r
  const int er = (lane >> 4) * 4;
  const int ec = lane & 15;
  const int r0 = mt * 128 + wm;
  const int c0 = nt * 128 + wn;

  if (EPI == 0) {
    u16* C = (u16*)Cv + sC * blockIdx.z;
    const float* bz = bias + blockIdx.z * 1024;
    const float zs = (blockIdx.z == 0) ? 0.03125f : 1.0f;  // fold 1/sqrt(1024) into Q
#pragma unroll
    for (int mi = 0; mi < 4; ++mi)
#pragma unroll
      for (int ni = 0; ni < 4; ++ni) {
        const int col = c0 + ni * 16 + ec;
        const float bb = bz[col];
#pragma unroll
        for (int r = 0; r < 4; ++r) {
          const int row = r0 + mi * 16 + er + r;
          C[(size_t)row * N + col] = f2bf((acc[mi][ni][r] + bb) * zs);
        }
      }
  } else if (EPI == 1) {
    // P~ = exp(s) (no max subtraction: |s| bounded ~11 worst case, fp32-safe),
    // accumulate row sums -> lsum for PV-side normalization.
    u16* C = (u16*)Cv + sC * blockIdx.z;
    float* lz = lsum + blockIdx.z * 2048;
#pragma unroll
    for (int mi = 0; mi < 4; ++mi) {
      float rs[4] = {0.f, 0.f, 0.f, 0.f};
#pragma unroll
      for (int ni = 0; ni < 4; ++ni) {
        const int col = c0 + ni * 16 + ec;
#pragma unroll
        for (int r = 0; r < 4; ++r) {
          const int row = r0 + mi * 16 + er + r;
          const float e = exp2f(acc[mi][ni][r] * 1.44269504088896340736f);
          C[(size_t)row * N + col] = f2bf(e);
          rs[r] += e;
        }
      }
      // reduce across the 16 lanes sharing each row (lane&15 = col within group)
#pragma unroll
      for (int o = 1; o < 16; o <<= 1)
#pragma unroll
        for (int r = 0; r < 4; ++r) rs[r] += __shfl_xor(rs[r], o);
      if ((lane & 15) == 0) {
#pragma unroll
        for (int r = 0; r < 4; ++r)
          atomicAdd(&lz[r0 + mi * 16 + er + r], rs[r]);
      }
    }
  } else {
    float* C = (float*)Cv + sC * blockIdx.z;
    const float* lz = lsum + blockIdx.z * 2048;
#pragma unroll
    for (int mi = 0; mi < 4; ++mi) {
      float inv[4];
#pragma unroll
      for (int r = 0; r < 4; ++r) inv[r] = 1.0f / lz[r0 + mi * 16 + er + r];
#pragma unroll
      for (int ni = 0; ni < 4; ++ni) {
        const int col = c0 + ni * 16 + ec;
#pragma unroll
        for (int r = 0; r < 4; ++r) {
          const int row = r0 + mi * 16 + er + r;
          C[(size_t)row * N + col] = acc[mi][ni][r] * inv[r];
        }
      }
    }
  }
}

extern "C" void kernel_launch(void* const* d_in, const int* in_sizes, int n_in,
                              void* d_out, int out_size, void* d_ws, size_t ws_size,
                              hipStream_t stream) {
  const float* x  = (const float*)d_in[0];
  const float* Wq = (const float*)d_in[1];
  const float* bq = (const float*)d_in[2];
  const float* Wk = (const float*)d_in[3];
  const float* bk = (const float*)d_in[4];
  const float* Wv = (const float*)d_in[5];
  const float* bv = (const float*)d_in[6];
  float* out = (float*)d_out;

  char* ws = (char*)d_ws;
  const size_t MB = 1ull << 20;
  u16* Q    = (u16*)(ws + 0 * MB);    // [3][8192][1024] bf16: Q,K,V contiguous
  u16* Kb   = (u16*)(ws + 16 * MB);
  u16* V    = (u16*)(ws + 32 * MB);
  u16* Vt   = (u16*)(ws + 48 * MB);   // [4][1024][2048]
  u16* Xb   = (u16*)(ws + 64 * MB);   // [8192][1024]
  u16* Wt   = (u16*)(ws + 80 * MB);   // [3][1024][1024]
  float* bias = (float*)(ws + 86 * MB);  // [3][1024]
  float* lsum = (float*)(ws + 87 * MB);  // [4][2048] softmax denominators
  u16* P    = (u16*)(ws + 88 * MB);   // [4][2048][2048] exp(scores), ends 120MB
  (void)Kb; (void)ws_size; (void)in_sizes; (void)n_in; (void)out_size;

  // 1) x -> bf16 (+ zero lsum)
  cvt_x<<<8192, 256, 0, stream>>>(x, Xb, lsum);
  // 2) W -> Wt bf16
  transpose_w<<<dim3(32, 32, 3), 256, 0, stream>>>(Wq, Wk, Wv, Wt);
  // 3) biases contiguous
  gather_bias<<<dim3(4, 3, 1), 256, 0, stream>>>(bq, bk, bv, bias);
  // 4) QKV projection (Q pre-scaled by 1/32), z = q/k/v.  m-tiles fastest -> A-stripe per XCD.
  gemm_bt<0, 0><<<dim3(64, 8, 3), 256, 0, stream>>>(
      Xb, Wt, Q, bias, nullptr, 8192, 1024, 1024,
      (size_t)0, (size_t)(1u << 20), (size_t)(8u << 20));
  // 5) V -> Vt
  transpose_v<<<dim3(32, 64, 4), 256, 0, stream>>>(V, Vt);
  // 6) P~ = exp(Q K^T), row sums -> lsum.  4x8 super-tile per XCD.
  gemm_bt<1, 1><<<dim3(256, 1, 4), 256, 0, stream>>>(
      Q, Kb, P, nullptr, lsum, 2048, 2048, 1024,
      (size_t)2097152, (size_t)2097152, (size_t)4194304);
  // 7) out = (P~ V) / lsum[row].  4x4 super-tile per XCD.
  gemm_bt<2, 2><<<dim3(128, 1, 4), 256, 0, stream>>>(
      P, Vt, out, nullptr, lsum, 2048, 1024, 2048,
      (size_t)4194304, (size_t)2097152, (size_t)2097152);
}

// Round 4
// 245.300 us; speedup vs baseline: 1.2745x; 1.2073x over previous
//
#include <hip/hip_runtime.h>
#include <hip/hip_bf16.h>
#include <stdint.h>

typedef unsigned short u16;
typedef __attribute__((ext_vector_type(8))) short short8;   // 8 x bf16 (4 VGPRs) MFMA A/B frag
typedef __attribute__((ext_vector_type(4))) float floatx4;  // MFMA C/D frag

#define BATCH 4
#define SEQ   2048
#define DIM   1024

__device__ inline u16 f2bf(float f) {
  union { float f; uint32_t u; } v; v.f = f;
  uint32_t r = v.u + 0x7fffu + ((v.u >> 16) & 1u);  // RNE
  return (u16)(r >> 16);
}
__device__ inline float bf2f(u16 h) {
  union { uint32_t u; float f; } v; v.u = ((uint32_t)h) << 16;
  return v.f;
}

// async global->LDS, 16B per lane; LDS dest is wave-uniform base (+lane*16 by HW)
__device__ inline void gload_lds16(const u16* g, u16* l) {
  __builtin_amdgcn_global_load_lds((const __attribute__((address_space(1))) uint32_t*)g,
                                   (__attribute__((address_space(3))) uint32_t*)l,
                                   16, 0, 0);
}

// ---------------- elementwise fp32 -> bf16 (+ zero the rowsum buffer) ----------------
__global__ __launch_bounds__(256) void cvt_x(const float* __restrict__ in,
                                             u16* __restrict__ out,
                                             float* __restrict__ lsum) {
  size_t i = ((size_t)blockIdx.x * 256 + threadIdx.x) * 4;
  float4 v = *(const float4*)(in + i);
  ushort4 o;
  o.x = f2bf(v.x); o.y = f2bf(v.y); o.z = f2bf(v.z); o.w = f2bf(v.w);
  *(ushort4*)(out + i) = o;
  if (blockIdx.x < 8) {  // zero 8192 floats of lsum
    float4 z = {0.f, 0.f, 0.f, 0.f};
    *(float4*)(lsum + (size_t)blockIdx.x * 1024 + threadIdx.x * 4) = z;
  }
}

// ---------------- W[d][h] fp32 -> Wt[h][d] bf16 (3 weights via z) ----------------
__global__ __launch_bounds__(256) void transpose_w(const float* __restrict__ Wq,
                                                   const float* __restrict__ Wk,
                                                   const float* __restrict__ Wv,
                                                   u16* __restrict__ out) {
  const float* W = (blockIdx.z == 0) ? Wq : (blockIdx.z == 1) ? Wk : Wv;
  u16* o = out + (size_t)blockIdx.z * (1u << 20);
  __shared__ u16 tile[32][33];
  int c0 = blockIdx.x * 32, r0 = blockIdx.y * 32;
  int tx = threadIdx.x & 31, ty = threadIdx.x >> 5;  // ty 0..7
#pragma unroll
  for (int p = 0; p < 4; ++p)
    tile[p * 8 + ty][tx] = f2bf(W[(size_t)(r0 + p * 8 + ty) * DIM + c0 + tx]);
  __syncthreads();
#pragma unroll
  for (int p = 0; p < 4; ++p)
    o[(size_t)(c0 + p * 8 + ty) * DIM + r0 + tx] = tile[tx][p * 8 + ty];
}

// ---------------- pack bq,bk,bv contiguously ----------------
__global__ void gather_bias(const float* __restrict__ bq, const float* __restrict__ bk,
                            const float* __restrict__ bv, float* __restrict__ out) {
  int i = blockIdx.x * 256 + threadIdx.x;  // 0..1023
  const float* s = (blockIdx.y == 0) ? bq : (blockIdx.y == 1) ? bk : bv;
  out[blockIdx.y * 1024 + i] = s[i];
}

// ---------------- bf16 GEMM, BK=64 (two 128x32 LDS slabs per barrier pair) ----------------
// C[m][n] = sum_k A[m][k] * Bt[n][k]
// EPI 0: (acc+bias[col])*zscale (z==0 -> 1/32: attention scale folded into Q), bf16 out.
// EPI 1: exp(acc), bf16 out, atomicAdd per-row sums into lsum.
// EPI 2: acc * (1/lsum[row]), fp32 out.
// EPI 3: acc + bias[row] (V bias), bf16, column-demuxed store into Vt[b][h][s].
// SWIZ 0: grid(64,8,z): mt=x, nt=y  (xcd = mt%8 -> A-stripe per XCD)
// SWIZ 1: grid(256,1,z): 4m x 8n super-tile per XCD
// SWIZ 2: grid(128,1,z): 4m x 4n super-tile per XCD
// SWIZ 3: grid(64,8,1): nt=x, mt=y  (xcd = nt%8 -> B-stripe per XCD; A small)
template <int EPI, int SWIZ>
__global__ __launch_bounds__(256, 3)
void gemm_bt(const u16* __restrict__ A, const u16* __restrict__ Bt,
             void* __restrict__ Cv, const float* __restrict__ bias,
             float* __restrict__ lsum, int M, int N, int K,
             size_t sA, size_t sB, size_t sC) {
  __shared__ u16 ldsA[128 * 64];   // two slabs of 128x32
  __shared__ u16 ldsB[128 * 64];
  const int lane = threadIdx.x & 63;
  const int wave = threadIdx.x >> 6;

  int mt, nt;
  if (SWIZ == 0) {
    mt = blockIdx.x; nt = blockIdx.y;
  } else if (SWIZ == 1) {
    const int lin = blockIdx.x;            // 0..255
    const int c = lin & 7, j = lin >> 3;   // xcd-slot, index within slot
    mt = 4 * (c & 3) + (j & 3);            // 16 m-tiles
    nt = 8 * (c >> 2) + (j >> 2);          // 16 n-tiles
  } else if (SWIZ == 2) {
    const int lin = blockIdx.x;            // 0..127
    const int c = lin & 7, j = lin >> 3;
    mt = 4 * (c >> 1) + (j & 3);           // 16 m-tiles
    nt = 4 * (c & 1) + (j >> 2);           // 8 n-tiles
  } else {
    nt = blockIdx.x; mt = blockIdx.y;
  }

  const u16* Ab = A + sA * blockIdx.z + (size_t)mt * 128 * K;
  const u16* Bb = Bt + sB * blockIdx.z + (size_t)nt * 128 * K;

  // staging (per slab identical to the verified BK=32 pattern):
  // wave w covers tile rows [w*32, w*32+32); 2 insts of 16 rows each per slab.
  const int sr = lane >> 2;          // row within 16-row group
  const int sc = (lane & 3) * 8;     // k-offset (elements), 16B chunks
  const u16* gA0 = Ab + (size_t)(wave * 32 + sr) * K + sc;
  const u16* gA1 = gA0 + (size_t)16 * K;
  const u16* gB0 = Bb + (size_t)(wave * 32 + sr) * K + sc;
  const u16* gB1 = gB0 + (size_t)16 * K;
  u16* lA0 = ldsA + wave * 1024;  // slab0: 16 rows * 32 elems = 512 per inst
  u16* lA1 = lA0 + 512;
  u16* lB0 = ldsB + wave * 1024;
  u16* lB1 = lB0 + 512;
  // slab1 lives at +4096 elems (128*32)

  // compute: 2x2 waves, each 64x64 = 4x4 subtiles of 16x16
  const int wm = (wave >> 1) * 64;
  const int wn = (wave & 1) * 64;
  const int fr = lane & 15;
  const int fk = (lane >> 4) * 8;
  const u16* la = ldsA + (wm + fr) * 32 + fk;
  const u16* lb = ldsB + (wn + fr) * 32 + fk;

  floatx4 acc[4][4] = {};

  for (int kt = 0; kt < K; kt += 64) {
    __syncthreads();
    gload_lds16(gA0 + kt, lA0);
    gload_lds16(gA1 + kt, lA1);
    gload_lds16(gA0 + kt + 32, lA0 + 4096);
    gload_lds16(gA1 + kt + 32, lA1 + 4096);
    gload_lds16(gB0 + kt, lB0);
    gload_lds16(gB1 + kt, lB1);
    gload_lds16(gB0 + kt + 32, lB0 + 4096);
    gload_lds16(gB1 + kt + 32, lB1 + 4096);
    __syncthreads();
#pragma unroll
    for (int ks = 0; ks < 2; ++ks) {
      short8 a[4], b[4];
#pragma unroll
      for (int i = 0; i < 4; ++i) a[i] = *(const short8*)(la + ks * 4096 + i * 512);
#pragma unroll
      for (int i = 0; i < 4; ++i) b[i] = *(const short8*)(lb + ks * 4096 + i * 512);
#pragma unroll
      for (int mi = 0; mi < 4; ++mi)
#pragma unroll
        for (int ni = 0; ni < 4; ++ni)
          acc[mi][ni] = __builtin_amdgcn_mfma_f32_16x16x32_bf16(a[mi], b[ni], acc[mi][ni], 0, 0, 0);
    }
  }

  // epilogue: C/D layout col=lane&15, row=(lane>>4)*4+r
  const int er = (lane >> 4) * 4;
  const int ec = lane & 15;
  const int r0 = mt * 128 + wm;
  const int c0 = nt * 128 + wn;

  if (EPI == 0) {
    u16* C = (u16*)Cv + sC * blockIdx.z;
    const float* bz = bias + blockIdx.z * 1024;
    const float zs = (blockIdx.z == 0) ? 0.03125f : 1.0f;  // fold 1/sqrt(1024) into Q
#pragma unroll
    for (int mi = 0; mi < 4; ++mi)
#pragma unroll
      for (int ni = 0; ni < 4; ++ni) {
        const int col = c0 + ni * 16 + ec;
        const float bb = bz[col];
#pragma unroll
        for (int r = 0; r < 4; ++r) {
          const int row = r0 + mi * 16 + er + r;
          C[(size_t)row * N + col] = f2bf((acc[mi][ni][r] + bb) * zs);
        }
      }
  } else if (EPI == 1) {
    // P~ = exp(s) (no max subtraction: |s| bounded, fp32-safe), row sums -> lsum.
    u16* C = (u16*)Cv + sC * blockIdx.z;
    float* lz = lsum + blockIdx.z * 2048;
#pragma unroll
    for (int mi = 0; mi < 4; ++mi) {
      float rs[4] = {0.f, 0.f, 0.f, 0.f};
#pragma unroll
      for (int ni = 0; ni < 4; ++ni) {
        const int col = c0 + ni * 16 + ec;
#pragma unroll
        for (int r = 0; r < 4; ++r) {
          const int row = r0 + mi * 16 + er + r;
          const float e = exp2f(acc[mi][ni][r] * 1.44269504088896340736f);
          C[(size_t)row * N + col] = f2bf(e);
          rs[r] += e;
        }
      }
#pragma unroll
      for (int o = 1; o < 16; o <<= 1)
#pragma unroll
        for (int r = 0; r < 4; ++r) rs[r] += __shfl_xor(rs[r], o);
      if ((lane & 15) == 0) {
#pragma unroll
        for (int r = 0; r < 4; ++r)
          atomicAdd(&lz[r0 + mi * 16 + er + r], rs[r]);
      }
    }
  } else if (EPI == 2) {
    float* C = (float*)Cv + sC * blockIdx.z;
    const float* lz = lsum + blockIdx.z * 2048;
#pragma unroll
    for (int mi = 0; mi < 4; ++mi) {
      float inv[4];
#pragma unroll
      for (int r = 0; r < 4; ++r) inv[r] = 1.0f / lz[r0 + mi * 16 + er + r];
#pragma unroll
      for (int ni = 0; ni < 4; ++ni) {
        const int col = c0 + ni * 16 + ec;
#pragma unroll
        for (int r = 0; r < 4; ++r) {
          const int row = r0 + mi * 16 + er + r;
          C[(size_t)row * N + col] = acc[mi][ni][r] * inv[r];
        }
      }
    }
  } else {
    // Vt[b][h][s]: rows m = h, cols n = global s (b = col>>11).
    u16* C = (u16*)Cv;
    const float* bz = bias + 2 * 1024;  // bv, indexed by row (=h)
#pragma unroll
    for (int mi = 0; mi < 4; ++mi) {
      float bb[4];
#pragma unroll
      for (int r = 0; r < 4; ++r) bb[r] = bz[r0 + mi * 16 + er + r];
#pragma unroll
      for (int ni = 0; ni < 4; ++ni) {
        const int col = c0 + ni * 16 + ec;
        const size_t base = (size_t)(col >> 11) * (1u << 21) + (col & 2047);
#pragma unroll
        for (int r = 0; r < 4; ++r) {
          const int row = r0 + mi * 16 + er + r;
          C[base + (size_t)row * 2048] = f2bf(acc[mi][ni][r] + bb[r]);
        }
      }
    }
  }
}

extern "C" void kernel_launch(void* const* d_in, const int* in_sizes, int n_in,
                              void* d_out, int out_size, void* d_ws, size_t ws_size,
                              hipStream_t stream) {
  const float* x  = (const float*)d_in[0];
  const float* Wq = (const float*)d_in[1];
  const float* bq = (const float*)d_in[2];
  const float* Wk = (const float*)d_in[3];
  const float* bk = (const float*)d_in[4];
  const float* Wv = (const float*)d_in[5];
  const float* bv = (const float*)d_in[6];
  float* out = (float*)d_out;

  char* ws = (char*)d_ws;
  const size_t MB = 1ull << 20;
  u16* Q    = (u16*)(ws + 0 * MB);    // [2][8192][1024] bf16: Q,K contiguous
  u16* Kb   = (u16*)(ws + 16 * MB);
  u16* Vt   = (u16*)(ws + 48 * MB);   // [4][1024][2048]
  u16* Xb   = (u16*)(ws + 64 * MB);   // [8192][1024]
  u16* Wt   = (u16*)(ws + 80 * MB);   // [3][1024][1024]
  float* bias = (float*)(ws + 86 * MB);  // [3][1024]
  float* lsum = (float*)(ws + 87 * MB);  // [4][2048] softmax denominators
  u16* P    = (u16*)(ws + 88 * MB);   // [4][2048][2048] exp(scores), ends 120MB
  (void)Kb; (void)ws_size; (void)in_sizes; (void)n_in; (void)out_size;

  // 1) x -> bf16 (+ zero lsum)
  cvt_x<<<8192, 256, 0, stream>>>(x, Xb, lsum);
  // 2) W -> Wt bf16
  transpose_w<<<dim3(32, 32, 3), 256, 0, stream>>>(Wq, Wk, Wv, Wt);
  // 3) biases contiguous
  gather_bias<<<dim3(4, 3, 1), 256, 0, stream>>>(bq, bk, bv, bias);
  // 4a) Q,K projection (Q pre-scaled by 1/32), z = q/k.  A-stripe per XCD.
  gemm_bt<0, 0><<<dim3(64, 8, 2), 256, 0, stream>>>(
      Xb, Wt, Q, bias, nullptr, 8192, 1024, 1024,
      (size_t)0, (size_t)(1u << 20), (size_t)(8u << 20));
  // 4b) Vt = Wv^T x^T + bv (direct transposed V projection).  B-stripe per XCD.
  gemm_bt<3, 3><<<dim3(64, 8, 1), 256, 0, stream>>>(
      Wt + 2 * (1u << 20), Xb, Vt, bias, nullptr, 1024, 8192, 1024,
      (size_t)0, (size_t)0, (size_t)0);
  // 5) P~ = exp(Q K^T), row sums -> lsum.  4x8 super-tile per XCD.
  gemm_bt<1, 1><<<dim3(256, 1, 4), 256, 0, stream>>>(
      Q, Kb, P, nullptr, lsum, 2048, 2048, 1024,
      (size_t)2097152, (size_t)2097152, (size_t)4194304);
  // 6) out = (P~ V) / lsum[row].  4x4 super-tile per XCD.
  gemm_bt<2, 2><<<dim3(128, 1, 4), 256, 0, stream>>>(
      P, Vt, out, nullptr, lsum, 2048, 1024, 2048,
      (size_t)4194304, (size_t)2097152, (size_t)2097152);
}

// Round 5
// 238.350 us; speedup vs baseline: 1.3116x; 1.0292x over previous
//
#include <hip/hip_runtime.h>
#include <hip/hip_bf16.h>
#include <stdint.h>

typedef unsigned short u16;
typedef __attribute__((ext_vector_type(8))) short short8;   // 8 x bf16 (4 VGPRs) MFMA A/B frag
typedef __attribute__((ext_vector_type(4))) float floatx4;  // MFMA C/D frag

#define BATCH 4
#define SEQ   2048
#define DIM   1024

__device__ inline u16 f2bf(float f) {
  union { float f; uint32_t u; } v; v.f = f;
  uint32_t r = v.u + 0x7fffu + ((v.u >> 16) & 1u);  // RNE
  return (u16)(r >> 16);
}

// async global->LDS, 16B per lane; LDS dest is wave-uniform base (+lane*16 by HW)
__device__ inline void gload_lds16(const u16* g, u16* l) {
  __builtin_amdgcn_global_load_lds((const __attribute__((address_space(1))) uint32_t*)g,
                                   (__attribute__((address_space(3))) uint32_t*)l,
                                   16, 0, 0);
}

// ---------------- elementwise fp32 -> bf16 (+ zero the rowsum buffer) ----------------
__global__ __launch_bounds__(256) void cvt_x(const float* __restrict__ in,
                                             u16* __restrict__ out,
                                             float* __restrict__ lsum) {
  size_t i = ((size_t)blockIdx.x * 256 + threadIdx.x) * 4;
  float4 v = *(const float4*)(in + i);
  ushort4 o;
  o.x = f2bf(v.x); o.y = f2bf(v.y); o.z = f2bf(v.z); o.w = f2bf(v.w);
  *(ushort4*)(out + i) = o;
  if (blockIdx.x < 8) {  // zero 8192 floats of lsum
    float4 z = {0.f, 0.f, 0.f, 0.f};
    *(float4*)(lsum + (size_t)blockIdx.x * 1024 + threadIdx.x * 4) = z;
  }
}

// ---------------- W[d][h] fp32 -> Wt[h][d] bf16 (3 weights via z) ----------------
__global__ __launch_bounds__(256) void transpose_w(const float* __restrict__ Wq,
                                                   const float* __restrict__ Wk,
                                                   const float* __restrict__ Wv,
                                                   u16* __restrict__ out) {
  const float* W = (blockIdx.z == 0) ? Wq : (blockIdx.z == 1) ? Wk : Wv;
  u16* o = out + (size_t)blockIdx.z * (1u << 20);
  __shared__ u16 tile[32][33];
  int c0 = blockIdx.x * 32, r0 = blockIdx.y * 32;
  int tx = threadIdx.x & 31, ty = threadIdx.x >> 5;  // ty 0..7
#pragma unroll
  for (int p = 0; p < 4; ++p)
    tile[p * 8 + ty][tx] = f2bf(W[(size_t)(r0 + p * 8 + ty) * DIM + c0 + tx]);
  __syncthreads();
#pragma unroll
  for (int p = 0; p < 4; ++p)
    o[(size_t)(c0 + p * 8 + ty) * DIM + r0 + tx] = tile[tx][p * 8 + ty];
}

// ---------------- pack bq,bk,bv contiguously ----------------
__global__ void gather_bias(const float* __restrict__ bq, const float* __restrict__ bk,
                            const float* __restrict__ bv, float* __restrict__ out) {
  int i = blockIdx.x * 256 + threadIdx.x;  // 0..1023
  const float* s = (blockIdx.y == 0) ? bq : (blockIdx.y == 1) ? bk : bv;
  out[blockIdx.y * 1024 + i] = s[i];
}

// ---------------- bf16 GEMM, BK=64 (two 32-k slabs per barrier pair) ----------------
// C[m][n] = sum_k A[m][k] * Bt[n][k].  Block tile TM x 128.
// TM=128: 4 waves of 64x64 (acc 4x4), 3 blocks/CU.
// TM=256: 4 waves of 128x64 (acc 8x4) -> 1.33x less LDS traffic per FLOP, 2 blocks/CU.
// EPI 0: (acc+bias[col])*zscale (z==0 -> 1/32), bf16 out.
// EPI 1: exp(acc), bf16 out, atomicAdd per-row sums into lsum.
// EPI 2: acc * (1/lsum[row]), fp32 out.
// EPI 3: acc + bias[row] (V bias), bf16, column-demuxed store into Vt[b][h][s].
// SWIZ 0: grid(M/TM,8,z): mt=x, nt=y   (xcd = mt%8 -> A-stripe per XCD)
// SWIZ 2: grid(128,1,z): mt 16, nt 8   (4m x 4n-ish super-tile per XCD)
// SWIZ 3: grid(64,8,1): nt=x, mt=y     (xcd = nt%8 -> B-stripe per XCD)
// SWIZ 4: grid(128,1,z): mt 8, nt 16   (TM=256 QK^T: 4m x 4n per XCD)
template <int EPI, int SWIZ, int TM>
__global__ __launch_bounds__(256, (TM == 256) ? 2 : 3)
void gemm_bt(const u16* __restrict__ A, const u16* __restrict__ Bt,
             void* __restrict__ Cv, const float* __restrict__ bias,
             float* __restrict__ lsum, int M, int N, int K,
             size_t sA, size_t sB, size_t sC) {
  constexpr int MI = TM / 32;          // acc rows of 16 per wave (4 or 8)
  constexpr int AS = TM / 64;          // A staging insts per wave per slab (2 or 4)
  __shared__ u16 ldsA[TM * 64];        // two slabs of TM x 32
  __shared__ u16 ldsB[128 * 64];
  const int lane = threadIdx.x & 63;
  const int wave = threadIdx.x >> 6;

  int mt, nt;
  if (SWIZ == 0) {
    mt = blockIdx.x; nt = blockIdx.y;
  } else if (SWIZ == 2) {
    const int lin = blockIdx.x;            // 0..127
    const int c = lin & 7, j = lin >> 3;   // xcd-slot, index within slot
    mt = 4 * (c >> 1) + (j & 3);           // 16 m-tiles
    nt = 4 * (c & 1) + (j >> 2);           // 8 n-tiles
  } else if (SWIZ == 3) {
    nt = blockIdx.x; mt = blockIdx.y;
  } else {
    const int lin = blockIdx.x;            // 0..127
    const int c = lin & 7, j = lin >> 3;
    mt = 4 * (c & 1) + (j & 3);            // 8 m-tiles
    nt = 4 * (c >> 1) + (j >> 2);          // 16 n-tiles
  }

  const u16* Ab = A + sA * blockIdx.z + (size_t)mt * TM * K;
  const u16* Bb = Bt + sB * blockIdx.z + (size_t)nt * 128 * K;

  // staging (slab layout = TM/128 rows x 32 k-els, row stride 64B, as measured-OK):
  // wave w covers A rows [w*TM/4, ...), B rows [w*32, ...); insts of 16 rows each.
  const int sr = lane >> 2;          // row within 16-row group
  const int sc = (lane & 3) * 8;     // k-offset (elements), 16B chunks
  const u16* gA0 = Ab + (size_t)(wave * (TM / 4) + sr) * K + sc;
  const u16* gB0 = Bb + (size_t)(wave * 32 + sr) * K + sc;
  u16* lA0 = ldsA + wave * (TM / 4) * 32;   // per 16-row inst: +512 els
  u16* lB0 = ldsB + wave * 1024;
  constexpr int SLA = TM * 32;       // A slab1 offset (elements)
  constexpr int SLB = 4096;          // B slab1 offset

  // compute: waves 2x2; wave tile (TM/2) x 64
  const int wm = (wave >> 1) * (TM / 2);
  const int wn = (wave & 1) * 64;
  const int fr = lane & 15;
  const int fk = (lane >> 4) * 8;
  const u16* la = ldsA + (wm + fr) * 32 + fk;
  const u16* lb = ldsB + (wn + fr) * 32 + fk;

  floatx4 acc[MI][4] = {};

  for (int kt = 0; kt < K; kt += 64) {
    __syncthreads();
#pragma unroll
    for (int i = 0; i < AS; ++i) {
      gload_lds16(gA0 + kt + (size_t)(16 * i) * K, lA0 + i * 512);
      gload_lds16(gA0 + kt + 32 + (size_t)(16 * i) * K, lA0 + SLA + i * 512);
    }
#pragma unroll
    for (int i = 0; i < 2; ++i) {
      gload_lds16(gB0 + kt + (size_t)(16 * i) * K, lB0 + i * 512);
      gload_lds16(gB0 + kt + 32 + (size_t)(16 * i) * K, lB0 + SLB + i * 512);
    }
    __syncthreads();
#pragma unroll
    for (int ks = 0; ks < 2; ++ks) {
      short8 a[MI], b[4];
#pragma unroll
      for (int i = 0; i < MI; ++i)
        a[i] = *(const short8*)(la + ks * SLA + i * 512);
#pragma unroll
      for (int i = 0; i < 4; ++i)
        b[i] = *(const short8*)(lb + ks * SLB + i * 512);
#pragma unroll
      for (int mi = 0; mi < MI; ++mi)
#pragma unroll
        for (int ni = 0; ni < 4; ++ni)
          acc[mi][ni] = __builtin_amdgcn_mfma_f32_16x16x32_bf16(a[mi], b[ni], acc[mi][ni], 0, 0, 0);
    }
  }

  // epilogue: C/D layout col=lane&15, row=(lane>>4)*4+r
  const int er = (lane >> 4) * 4;
  const int ec = lane & 15;
  const int r0 = mt * TM + wm;
  const int c0 = nt * 128 + wn;

  if (EPI == 0) {
    u16* C = (u16*)Cv + sC * blockIdx.z;
    const float* bz = bias + blockIdx.z * 1024;
    const float zs = (blockIdx.z == 0) ? 0.03125f : 1.0f;  // fold 1/sqrt(1024) into Q
#pragma unroll
    for (int mi = 0; mi < MI; ++mi)
#pragma unroll
      for (int ni = 0; ni < 4; ++ni) {
        const int col = c0 + ni * 16 + ec;
        const float bb = bz[col];
#pragma unroll
        for (int r = 0; r < 4; ++r) {
          const int row = r0 + mi * 16 + er + r;
          C[(size_t)row * N + col] = f2bf((acc[mi][ni][r] + bb) * zs);
        }
      }
  } else if (EPI == 1) {
    // P~ = exp(s) (no max subtraction: |s| bounded, fp32-safe), row sums -> lsum.
    u16* C = (u16*)Cv + sC * blockIdx.z;
    float* lz = lsum + blockIdx.z * 2048;
#pragma unroll
    for (int mi = 0; mi < MI; ++mi) {
      float rs[4] = {0.f, 0.f, 0.f, 0.f};
#pragma unroll
      for (int ni = 0; ni < 4; ++ni) {
        const int col = c0 + ni * 16 + ec;
#pragma unroll
        for (int r = 0; r < 4; ++r) {
          const int row = r0 + mi * 16 + er + r;
          const float e = exp2f(acc[mi][ni][r] * 1.44269504088896340736f);
          C[(size_t)row * N + col] = f2bf(e);
          rs[r] += e;
        }
      }
#pragma unroll
      for (int o = 1; o < 16; o <<= 1)
#pragma unroll
        for (int r = 0; r < 4; ++r) rs[r] += __shfl_xor(rs[r], o);
      if ((lane & 15) == 0) {
#pragma unroll
        for (int r = 0; r < 4; ++r)
          atomicAdd(&lz[r0 + mi * 16 + er + r], rs[r]);
      }
    }
  } else if (EPI == 2) {
    float* C = (float*)Cv + sC * blockIdx.z;
    const float* lz = lsum + blockIdx.z * 2048;
#pragma unroll
    for (int mi = 0; mi < MI; ++mi) {
      float inv[4];
#pragma unroll
      for (int r = 0; r < 4; ++r) inv[r] = 1.0f / lz[r0 + mi * 16 + er + r];
#pragma unroll
      for (int ni = 0; ni < 4; ++ni) {
        const int col = c0 + ni * 16 + ec;
#pragma unroll
        for (int r = 0; r < 4; ++r) {
          const int row = r0 + mi * 16 + er + r;
          C[(size_t)row * N + col] = acc[mi][ni][r] * inv[r];
        }
      }
    }
  } else {
    // Vt[b][h][s]: rows m = h, cols n = global s (b = col>>11).
    u16* C = (u16*)Cv;
    const float* bz = bias + 2 * 1024;  // bv, indexed by row (=h)
#pragma unroll
    for (int mi = 0; mi < MI; ++mi) {
      float bb[4];
#pragma unroll
      for (int r = 0; r < 4; ++r) bb[r] = bz[r0 + mi * 16 + er + r];
#pragma unroll
      for (int ni = 0; ni < 4; ++ni) {
        const int col = c0 + ni * 16 + ec;
        const size_t base = (size_t)(col >> 11) * (1u << 21) + (col & 2047);
#pragma unroll
        for (int r = 0; r < 4; ++r) {
          const int row = r0 + mi * 16 + er + r;
          C[base + (size_t)row * 2048] = f2bf(acc[mi][ni][r] + bb[r]);
        }
      }
    }
  }
}

extern "C" void kernel_launch(void* const* d_in, const int* in_sizes, int n_in,
                              void* d_out, int out_size, void* d_ws, size_t ws_size,
                              hipStream_t stream) {
  const float* x  = (const float*)d_in[0];
  const float* Wq = (const float*)d_in[1];
  const float* bq = (const float*)d_in[2];
  const float* Wk = (const float*)d_in[3];
  const float* bk = (const float*)d_in[4];
  const float* Wv = (const float*)d_in[5];
  const float* bv = (const float*)d_in[6];
  float* out = (float*)d_out;

  char* ws = (char*)d_ws;
  const size_t MB = 1ull << 20;
  u16* Q    = (u16*)(ws + 0 * MB);    // [2][8192][1024] bf16: Q,K contiguous
  u16* Kb   = (u16*)(ws + 16 * MB);
  u16* Vt   = (u16*)(ws + 48 * MB);   // [4][1024][2048]
  u16* Xb   = (u16*)(ws + 64 * MB);   // [8192][1024]
  u16* Wt   = (u16*)(ws + 80 * MB);   // [3][1024][1024]
  float* bias = (float*)(ws + 86 * MB);  // [3][1024]
  float* lsum = (float*)(ws + 87 * MB);  // [4][2048] softmax denominators
  u16* P    = (u16*)(ws + 88 * MB);   // [4][2048][2048] exp(scores), ends 120MB
  (void)Kb; (void)ws_size; (void)in_sizes; (void)n_in; (void)out_size;

  // 1) x -> bf16 (+ zero lsum)
  cvt_x<<<8192, 256, 0, stream>>>(x, Xb, lsum);
  // 2) W -> Wt bf16
  transpose_w<<<dim3(32, 32, 3), 256, 0, stream>>>(Wq, Wk, Wv, Wt);
  // 3) biases contiguous
  gather_bias<<<dim3(4, 3, 1), 256, 0, stream>>>(bq, bk, bv, bias);
  // 4a) Q,K projection (Q pre-scaled by 1/32), z = q/k.  TM=256, A-stripe per XCD.
  gemm_bt<0, 0, 256><<<dim3(32, 8, 2), 256, 0, stream>>>(
      Xb, Wt, Q, bias, nullptr, 8192, 1024, 1024,
      (size_t)0, (size_t)(1u << 20), (size_t)(8u << 20));
  // 4b) Vt = Wv^T x^T + bv (direct transposed V projection).  TM=128, B-stripe per XCD.
  gemm_bt<3, 3, 128><<<dim3(64, 8, 1), 256, 0, stream>>>(
      Wt + 2 * (1u << 20), Xb, Vt, bias, nullptr, 1024, 8192, 1024,
      (size_t)0, (size_t)0, (size_t)0);
  // 5) P~ = exp(Q K^T), row sums -> lsum.  TM=256, 4x4 super-tile per XCD.
  gemm_bt<1, 4, 256><<<dim3(128, 1, 4), 256, 0, stream>>>(
      Q, Kb, P, nullptr, lsum, 2048, 2048, 1024,
      (size_t)2097152, (size_t)2097152, (size_t)4194304);
  // 6) out = (P~ V) / lsum[row].  TM=128, 4x4-ish super-tile per XCD.
  gemm_bt<2, 2, 128><<<dim3(128, 1, 4), 256, 0, stream>>>(
      P, Vt, out, nullptr, lsum, 2048, 1024, 2048,
      (size_t)4194304, (size_t)2097152, (size_t)2097152);
}